// Round 19
// baseline (134.230 us; speedup 1.0000x reference)
//
#include <hip/hip_runtime.h>
#include <hip/hip_bf16.h>
#include <math.h>

typedef __attribute__((ext_vector_type(8))) short short8;
typedef __attribute__((ext_vector_type(4))) float f32x4;

#define S_LEN   2048
#define DMODEL  1024
#define NHEAD   16
#define HDK     64
#define NBATCH  2
#define MTOT    (NBATCH*S_LEN)   // 4096
#define LOG2E   1.4426950408889634f

__device__ __forceinline__ unsigned short f2bf(float f) {
  union { float f; unsigned u; } c; c.f = f;
  unsigned r = c.u + 0x7FFFu + ((c.u >> 16) & 1u);
  return (unsigned short)(r >> 16);
}

__device__ __forceinline__ short8 lds_ld16(const unsigned short* p) {
  return *reinterpret_cast<const short8*>(p);   // 16B-aligned load
}

__device__ __forceinline__ void gload_lds16(const unsigned short* g, unsigned short* l) {
  __builtin_amdgcn_global_load_lds(
      (const __attribute__((address_space(1))) unsigned int*)g,
      (__attribute__((address_space(3))) unsigned int*)l, 16, 0, 0);
}

// ---------- fused prep: rmsnorm (blocks 0..4095) + weight transpose (4096..8191)
//            + bias table (8192..8447) + exp(gate) (8448..8463) ----------
__global__ __launch_bounds__(256) void fused_prep_kernel(
    const float* __restrict__ hs, const float* __restrict__ lnw,
    const float* __restrict__ rel_emb, const float* __restrict__ gmask,
    const float* __restrict__ qw, const float* __restrict__ kw,
    const float* __restrict__ vw, const float* __restrict__ ow,
    unsigned short* __restrict__ xo, float* __restrict__ btab,
    float* __restrict__ egf, unsigned short* __restrict__ egb,
    unsigned short* __restrict__ wqkv, unsigned short* __restrict__ wo) {
  const int blk = blockIdx.x, t = threadIdx.x;
  if (blk < MTOT) {
    // ---- RMSNorm -> bf16 ----
    const int row = blk;
    const float4 v = ((const float4*)(hs + (size_t)row*DMODEL))[t];
    float ss = v.x*v.x + v.y*v.y + v.z*v.z + v.w*v.w;
    #pragma unroll
    for (int off = 32; off >= 1; off >>= 1) ss += __shfl_xor(ss, off, 64);
    __shared__ float wsum[4];
    if ((t & 63) == 0) wsum[t >> 6] = ss;
    __syncthreads();
    float tot = wsum[0] + wsum[1] + wsum[2] + wsum[3];
    float sc = rsqrtf(tot * (1.0f/DMODEL) + 1e-6f);
    const float4 lw = ((const float4*)lnw)[t];
    uint2 o;
    o.x = (unsigned)f2bf(v.x*sc*lw.x) | ((unsigned)f2bf(v.y*sc*lw.y) << 16);
    o.y = (unsigned)f2bf(v.z*sc*lw.z) | ((unsigned)f2bf(v.w*sc*lw.w) << 16);
    ((uint2*)(xo + (size_t)row*DMODEL))[t] = o;
  } else if (blk < MTOT + 4096) {
    // ---- weight transpose + bf16: w[k][n] -> wt[n][k] ----
    int bb = blk - MTOT;
    int z = bb >> 10, rem = bb & 1023;
    const float* src = (z==0)?qw:(z==1)?kw:(z==2)?vw:ow;
    unsigned short* dst = (z<3) ? (wqkv + (size_t)z*DMODEL*DMODEL) : wo;
    __shared__ float tile[32][33];
    int n0 = (rem & 31)*32, k0 = (rem >> 5)*32;
    int tx = t & 31, ty = t >> 5;
    for (int r = ty; r < 32; r += 8)
      tile[r][tx] = src[(size_t)(k0+r)*DMODEL + n0 + tx];
    __syncthreads();
    for (int r = ty; r < 32; r += 8)
      dst[(size_t)(n0+r)*DMODEL + k0 + tx] = f2bf(tile[tx][r]);
  } else if (blk < MTOT + 4096 + 256) {
    // ---- relative-position bias table: btab[h][rel+2047], pre-scaled by log2e ----
    int idx = (blk - MTOT - 4096)*256 + t;
    if (idx >= NHEAD*4095) return;
    int h = idx / 4095, rp = idx % 4095, rel = rp - 2047;
    int bucket = (rel > 0) ? 16 : 0;
    int n = (rel < 0) ? -rel : rel;
    int v;
    if (n < 8) v = n;
    else {
      float lrv = logf((float)n * 0.125f) / 2.7725887f * 8.0f;  // log(n/8)/log(16)*8
      v = 8 + (int)lrv;
      if (v > 15) v = 15;
    }
    btab[idx] = rel_emb[(size_t)(bucket + v)*NHEAD + h] * LOG2E;
  } else {
    // ---- gate exponentials: egf = exp(gate) f32, egb = bf16 ----
    int i = (blk - MTOT - 4096 - 256)*256 + t;   // 0..4095
    float e = __expf(gmask[i]);
    egf[i] = e;
    egb[i] = f2bf(e);
  }
}

// ---------- 128x128 tile MFMA GEMM, BK=64, swizzled staging (r14/r16 proven) ----------
// EPI=0 (fused projections), z: 0 -> q*log2e [BH][S][64]; 1 -> k [BH][S][64];
//                            2 -> V'^T = exp(gate)*v in [B][1024][S] (block roles swapped)
// EPI=1: write f32 Of = resid + acc
template<int EPI>
__global__ __launch_bounds__(256) void gemm128(
    const unsigned short* __restrict__ X,
    const unsigned short* __restrict__ W,
    unsigned short* __restrict__ Oq, unsigned short* __restrict__ Ok,
    unsigned short* __restrict__ Ov,
    const float* __restrict__ resid, float* __restrict__ Of,
    const float* __restrict__ escale) {
  __shared__ unsigned short As[128*64];   // [row][granule ^ (row&7)], linear dest
  __shared__ unsigned short Bs[128*64];
  const int z = blockIdx.z;
  int m0, n0;
  const unsigned short *Ap, *Bp;
  if (EPI == 0 && z == 2) {               // V'^T: A = Wv (1024 rows), B = x (4096 rows)
    m0 = blockIdx.y*128; n0 = blockIdx.x*128;
    Ap = W + (size_t)2*DMODEL*DMODEL; Bp = X;
  } else {
    m0 = blockIdx.x*128; n0 = blockIdx.y*128;
    Ap = X; Bp = W + ((EPI==0) ? (size_t)z*DMODEL*DMODEL : 0);
  }
  const int t = threadIdx.x, lane = t & 63, w = t >> 6;
  const int g = lane >> 4, lr = lane & 15;
  const int wr = (w >> 1)*64, wc = (w & 1)*64;

  f32x4 acc[4][4];
  #pragma unroll
  for (int mi = 0; mi < 4; mi++)
    #pragma unroll
    for (int ni = 0; ni < 4; ni++) acc[mi][ni] = (f32x4){0.f,0.f,0.f,0.f};

  const unsigned short* ag[4]; const unsigned short* bg[4];
  unsigned short* al[4]; unsigned short* bl[4];
  #pragma unroll
  for (int i = 0; i < 4; i++) {
    int slot = t + i*256, row = slot >> 3, c8 = slot & 7;
    int cs = c8 ^ (row & 7);
    ag[i] = Ap + (size_t)(m0 + row)*DMODEL + cs*8;
    bg[i] = Bp + (size_t)(n0 + row)*DMODEL + cs*8;
    al[i] = As + slot*8;
    bl[i] = Bs + slot*8;
  }

  for (int kk = 0; kk < DMODEL; kk += 64) {
    #pragma unroll
    for (int i = 0; i < 4; i++) {
      gload_lds16(ag[i] + kk, al[i]);
      gload_lds16(bg[i] + kk, bl[i]);
    }
    __syncthreads();            // drains vmcnt -> tile staged
    #pragma unroll
    for (int ks = 0; ks < 2; ks++) {
      short8 af[4], bfr[4];
      #pragma unroll
      for (int mi = 0; mi < 4; mi++) {
        int R = wr + mi*16 + lr;
        af[mi] = lds_ld16(As + R*64 + (((ks*4 + g) ^ (R & 7)) << 3));
      }
      #pragma unroll
      for (int ni = 0; ni < 4; ni++) {
        int R = wc + ni*16 + lr;
        bfr[ni] = lds_ld16(Bs + R*64 + (((ks*4 + g) ^ (R & 7)) << 3));
      }
      #pragma unroll
      for (int mi = 0; mi < 4; mi++)
        #pragma unroll
        for (int ni = 0; ni < 4; ni++)
          acc[mi][ni] = __builtin_amdgcn_mfma_f32_16x16x32_bf16(af[mi], bfr[ni], acc[mi][ni], 0, 0, 0);
    }
    __syncthreads();            // reads done before next stage
  }

  if (EPI == 0) {
    if (z < 2) {
      unsigned short* dst = (z == 0) ? Oq : Ok;
      const float osc = (z == 0) ? LOG2E : 1.0f;
      #pragma unroll
      for (int mi = 0; mi < 4; mi++) {
        #pragma unroll
        for (int r = 0; r < 4; r++) {
          int m = m0 + wr + mi*16 + g*4 + r;
          int b = m >> 11, s = m & (S_LEN-1);
          unsigned short* drow = dst + ((size_t)b*NHEAD*S_LEN + s)*HDK;
          #pragma unroll
          for (int ni = 0; ni < 4; ni++) {
            int n = n0 + wc + ni*16 + lr;
            int h = n >> 6, dcol = n & 63;
            drow[(size_t)h*S_LEN*HDK + dcol] = f2bf(acc[mi][ni][r] * osc);
          }
        }
      }
    } else {
      #pragma unroll
      for (int ni = 0; ni < 4; ni++) {
        int n = n0 + wc + ni*16 + lr;
        int b = n >> 11, s = n & (S_LEN-1);
        float e = escale[n];                 // exp(gate) folded into V'
        #pragma unroll
        for (int mi = 0; mi < 4; mi++)
          #pragma unroll
          for (int r = 0; r < 4; r++) {
            int m = m0 + wr + mi*16 + g*4 + r;
            Ov[((size_t)b*DMODEL + m)*S_LEN + s] = f2bf(acc[mi][ni][r] * e);
          }
      }
    }
  } else {
    #pragma unroll
    for (int mi = 0; mi < 4; mi++) {
      #pragma unroll
      for (int r = 0; r < 4; r++) {
        int m = m0 + wr + mi*16 + g*4 + r;
        const float* rrow = resid + (size_t)m*DMODEL;
        float* orow = Of + (size_t)m*DMODEL;
        #pragma unroll
        for (int ni = 0; ni < 4; ni++) {
          int n = n0 + wc + ni*16 + lr;
          orow[n] = rrow[n] + acc[mi][ni][r];
        }
      }
    }
  }
}

// ---------- flash attention: r16 base + explicit A/B phase interleave (T15/sm-split) ----------
// Phases per tile: QK(A)+QK(B) MFMA cluster -> SM(A) -> PACK(A) -> SM(B) [VALU filler
// covering prowA write->read] -> PV(A) -> PACK(B) -> staging ds_writes [filler covering
// prowB] -> PV(B). MFMA and VALU pipes overlap (m114); fillers hide the lgkm hops.
// Pl doubled to per-set buffers so PACK(B) can't clobber PV(A)'s operand.
__global__ __launch_bounds__(256, 2) void attn_kernel(
    const unsigned short* __restrict__ Qg,
    const unsigned short* __restrict__ Kg,
    const unsigned short* __restrict__ Vtg,
    const float* __restrict__ btab,
    const unsigned short* __restrict__ egb,
    unsigned short* __restrict__ Og) {
  __shared__ __align__(16) unsigned short Kl[2][64][64];     // [buf][key][d-granule ^ key&7]
  __shared__ __align__(16) unsigned short Vl[2][64][64];     // [buf][d][key-granule ^ d&7]
  __shared__ __align__(16) unsigned short Pl[4][2][16*64];   // [wave][set][q][key-gran ^ q&7]

  const int flat = blockIdx.x;
  const int xcd = flat & 7, j = flat >> 3;
  const int bh = xcd*4 + (j >> 4), qx = j & 15;
  const int b = bh >> 4, h = bh & 15;
  const int q0 = qx * 128;

  const int t = threadIdx.x, w = t >> 6, lane = t & 63;
  const int g = lane >> 4, lr = lane & 15, l7 = lane & 7;
  const int srow0 = t >> 3, sg0 = t & 7, srow1 = srow0 + 32;
  const int swz = (sg0 ^ (srow0 & 7)) << 3;                // srow1&7 == srow0&7

  const unsigned short* Qb = Qg  + (size_t)bh*S_LEN*HDK;
  const unsigned short* Kb = Kg  + (size_t)bh*S_LEN*HDK;
  const unsigned short* Vb = Vtg + (size_t)bh*HDK*S_LEN;   // [d][s], gate-folded
  const unsigned short* ge = egb + (size_t)b*S_LEN;        // exp(gate) bf16

  // ---- Q fragments: wave owns q rows [q0+w*32, +32), two sets of 16 ----
  const int qs0A = q0 + w*32, qs0B = qs0A + 16;
  short8 qfA0 = *reinterpret_cast<const short8*>(Qb + (size_t)(qs0A+lr)*HDK + g*8);
  short8 qfA1 = *reinterpret_cast<const short8*>(Qb + (size_t)(qs0A+lr)*HDK + 32 + g*8);
  short8 qfB0 = *reinterpret_cast<const short8*>(Qb + (size_t)(qs0B+lr)*HDK + g*8);
  short8 qfB1 = *reinterpret_cast<const short8*>(Qb + (size_t)(qs0B+lr)*HDK + 32 + g*8);

  f32x4 accA[4], accB[4], l4A, l4B;
  #pragma unroll
  for (int n = 0; n < 4; n++) { accA[n] = (f32x4){0.f,0.f,0.f,0.f}; accB[n] = (f32x4){0.f,0.f,0.f,0.f}; }
  l4A = (f32x4){0.f,0.f,0.f,0.f}; l4B = (f32x4){0.f,0.f,0.f,0.f};

  const float* btb = btab + (size_t)h*4095 + 2047;
  const float cpos = btb[91];    // bucket saturates for |rel| >= 91
  const float cneg = btb[-91];

  // ---- prologue: stage tile 0 ----
  {
    *reinterpret_cast<uint4*>(&Kl[0][srow0][swz]) =
        *reinterpret_cast<const uint4*>(Kb + (size_t)srow0*HDK + sg0*8);
    *reinterpret_cast<uint4*>(&Kl[0][srow1][swz]) =
        *reinterpret_cast<const uint4*>(Kb + (size_t)srow1*HDK + sg0*8);
    *reinterpret_cast<uint4*>(&Vl[0][srow0][swz]) =
        *reinterpret_cast<const uint4*>(Vb + (size_t)srow0*S_LEN + sg0*8);
    *reinterpret_cast<uint4*>(&Vl[0][srow1][swz]) =
        *reinterpret_cast<const uint4*>(Vb + (size_t)srow1*S_LEN + sg0*8);
  }

  char* prowA = (char*)&Pl[w][0][0] + lr*128;   // this lane's P row (q = lr), set A
  char* prowB = (char*)&Pl[w][1][0] + lr*128;   // set B

  int cur = 0;
  const int NT = S_LEN/64;
  for (int kt = 0; kt < NT; ++kt) {
    const int key0 = kt*64;
    __syncthreads();   // buf[cur] staged; all reads of buf[cur^1] done

    uint4 nk0, nk1, nv0, nv1;
    const bool pf = (kt + 1 < NT);
    if (pf) {
      nk0 = *reinterpret_cast<const uint4*>(Kb + (size_t)(key0+64+srow0)*HDK + sg0*8);
      nk1 = *reinterpret_cast<const uint4*>(Kb + (size_t)(key0+64+srow1)*HDK + sg0*8);
      nv0 = *reinterpret_cast<const uint4*>(Vb + (size_t)srow0*S_LEN + key0+64 + sg0*8);
      nv1 = *reinterpret_cast<const uint4*>(Vb + (size_t)srow1*S_LEN + key0+64 + sg0*8);
    }

    // ---- K fragments (A-frag: row=key=n*16+lr, k=d) ----
    short8 bk[4][2];
    #pragma unroll
    for (int n = 0; n < 4; n++) {
      const unsigned short* kr = &Kl[cur][n*16 + lr][0];
      bk[n][0] = lds_ld16(kr + ((g ^ l7) << 3));
      bk[n][1] = lds_ld16(kr + (((4 + g) ^ l7) << 3));
    }
    // ---- V' fragments (B-frag: k=key, col=d=n*16+lr), shared by both sets ----
    short8 bv[2][4];
    #pragma unroll
    for (int c = 0; c < 2; c++)
      #pragma unroll
      for (int n = 0; n < 4; n++)
        bv[c][n] = lds_ld16(&Vl[cur][n*16 + lr][((4*c + g) ^ l7) << 3]);
    // ---- G fragments: col0 = exp(gate_k), cols1-15 = 0 (from global, L1-hot) ----
    short8 gv[2];
    #pragma unroll
    for (int c = 0; c < 2; c++) {
      short8 z8 = (short8){0,0,0,0,0,0,0,0};
      if (lr == 0)
        z8 = *reinterpret_cast<const short8*>(ge + key0 + c*32 + g*8);
      gv[c] = z8;
    }

    // ---- phase 1: QK^T MFMA cluster, BOTH sets (independent streams) ----
    const int dbA = key0 - qs0A, dbB = key0 - qs0B;
    const bool bandA = (dbA > -154 && dbA < 106);
    const bool bandB = (dbB > -154 && dbB < 106);
    const float ccA = bandA ? 0.f : ((dbA > 0) ? cpos : cneg);
    const float ccB = bandB ? 0.f : ((dbB > 0) ? cpos : cneg);
    f32x4 svA[4], svB[4];
    {
      f32x4 zA = (f32x4){ccA,ccA,ccA,ccA}, zB = (f32x4){ccB,ccB,ccB,ccB};
      __builtin_amdgcn_s_setprio(1);
      #pragma unroll
      for (int n = 0; n < 4; n++) {
        svA[n] = __builtin_amdgcn_mfma_f32_16x16x32_bf16(bk[n][0], qfA0, zA, 0, 0, 0);
        svB[n] = __builtin_amdgcn_mfma_f32_16x16x32_bf16(bk[n][0], qfB0, zB, 0, 0, 0);
      }
      #pragma unroll
      for (int n = 0; n < 4; n++) {
        svA[n] = __builtin_amdgcn_mfma_f32_16x16x32_bf16(bk[n][1], qfA1, svA[n], 0, 0, 0);
        svB[n] = __builtin_amdgcn_mfma_f32_16x16x32_bf16(bk[n][1], qfB1, svB[n], 0, 0, 0);
      }
      __builtin_amdgcn_s_setprio(0);
    }

#define SM_PHASE(sv_, band_, db_)                                                     \
    {                                                                                 \
      if (band_) {                                                                    \
        const float* btq = btb + ((db_) - lr);                                        \
        _Pragma("unroll") for (int n = 0; n < 4; n++)                                 \
          _Pragma("unroll") for (int r = 0; r < 4; r++)                               \
            sv_[n][r] += btq[n*16 + g*4 + r];                                         \
      }                                                                               \
      _Pragma("unroll") for (int n = 0; n < 4; n++)                                   \
        _Pragma("unroll") for (int r = 0; r < 4; r++)                                 \
          sv_[n][r] = exp2f(sv_[n][r]);                                               \
    }
#define PACK_PHASE(sv_, prow_)                                                        \
    {                                                                                 \
      _Pragma("unroll") for (int n = 0; n < 4; n++) {                                 \
        unsigned plo_, phi_;                                                          \
        asm("v_cvt_pk_bf16_f32 %0, %1, %2" : "=v"(plo_) : "v"(sv_[n][0]), "v"(sv_[n][1])); \
        asm("v_cvt_pk_bf16_f32 %0, %1, %2" : "=v"(phi_) : "v"(sv_[n][2]), "v"(sv_[n][3])); \
        uint2 pw_; pw_.x = plo_; pw_.y = phi_;                                        \
        *reinterpret_cast<uint2*>((prow_) + ((((2*n + (g>>1)) ^ l7) << 4) + ((g & 1) << 3))) = pw_; \
      }                                                                               \
    }
#define PV_PHASE(prow_, acc_, l4_)                                                    \
    {                                                                                 \
      _Pragma("unroll") for (int c = 0; c < 2; c++) {                                 \
        short8 pa_ = lds_ld16((const unsigned short*)((prow_) + (((4*c + g) ^ l7) << 4))); \
        __builtin_amdgcn_s_setprio(1);                                                \
        _Pragma("unroll") for (int n = 0; n < 4; n++)                                 \
          acc_[n] = __builtin_amdgcn_mfma_f32_16x16x32_bf16(pa_, bv[c][n], acc_[n], 0, 0, 0); \
        l4_ = __builtin_amdgcn_mfma_f32_16x16x32_bf16(pa_, gv[c], l4_, 0, 0, 0);      \
        __builtin_amdgcn_s_setprio(0);                                                \
      }                                                                               \
    }

    SM_PHASE(svA, bandA, dbA)          // phase 2: softmax A (VALU)
    PACK_PHASE(svA, prowA)             // phase 3: pack A -> LDS
    SM_PHASE(svB, bandB, dbB)          // phase 4: softmax B (covers prowA lgkm)
    PV_PHASE(prowA, accA, l4A)         // phase 5: PV A (MFMA)
    PACK_PHASE(svB, prowB)             // phase 6: pack B -> LDS
    if (pf) {                          // phase 7: staging writes (covers prowB lgkm)
      *reinterpret_cast<uint4*>(&Kl[cur^1][srow0][swz]) = nk0;
      *reinterpret_cast<uint4*>(&Kl[cur^1][srow1][swz]) = nk1;
      *reinterpret_cast<uint4*>(&Vl[cur^1][srow0][swz]) = nv0;
      *reinterpret_cast<uint4*>(&Vl[cur^1][srow1][swz]) = nv1;
    }
    PV_PHASE(prowB, accB, l4B)         // phase 8: PV B (MFMA)
#undef SM_PHASE
#undef PACK_PHASE
#undef PV_PHASE

    cur ^= 1;
  }

  // ---- finalize: l(q=g*4+r) lives on lane g*16 (col 0), reg r; denom = l + 1 ----
#define FINAL_SET(acc_, l4_, qs0_)                                                    \
  {                                                                                   \
    _Pragma("unroll") for (int r = 0; r < 4; r++) {                                   \
      float lq = __shfl(l4_[r], g*16);                                                \
      float inv = 1.0f / (lq + 1.0f);                                                 \
      int srw = (qs0_) + g*4 + r;                                                     \
      unsigned short* orow = Og + ((size_t)b*S_LEN + srw)*DMODEL + h*HDK;             \
      _Pragma("unroll") for (int n = 0; n < 4; n++)                                   \
        orow[n*16 + lr] = f2bf(acc_[n][r] * inv);                                     \
    }                                                                                 \
  }
  FINAL_SET(accA, l4A, qs0A)
  FINAL_SET(accB, l4B, qs0B)
#undef FINAL_SET
}

extern "C" void kernel_launch(void* const* d_in, const int* in_sizes, int n_in,
                              void* d_out, int out_size, void* d_ws, size_t ws_size,
                              hipStream_t stream) {
  const float* hs   = (const float*)d_in[0];
  const float* gate = (const float*)d_in[1];
  const float* lnw  = (const float*)d_in[2];
  const float* qw   = (const float*)d_in[3];
  const float* kw   = (const float*)d_in[4];
  const float* vw   = (const float*)d_in[5];
  const float* ow   = (const float*)d_in[6];
  const float* rel  = (const float*)d_in[7];
  float* out = (float*)d_out;

  char* ws = (char*)d_ws;
  const size_t MB = 1ull << 20;
  unsigned short* xbf  = (unsigned short*)(ws);            // 8 MB  x (bf16)
  unsigned short* wqkv = (unsigned short*)(ws + 8*MB);     // 6 MB  q/k/v weights^T
  unsigned short* wo   = (unsigned short*)(ws + 14*MB);    // 2 MB  o weight^T
  unsigned short* qb   = (unsigned short*)(ws + 16*MB);    // 8 MB  q [BH][S][64] (log2e-scaled)
  unsigned short* kb   = (unsigned short*)(ws + 24*MB);    // 8 MB  k [BH][S][64]
  unsigned short* vt   = (unsigned short*)(ws + 32*MB);    // 8 MB  v'^T [B][1024][S] (gate-folded)
  unsigned short* ao   = (unsigned short*)(ws + 40*MB);    // 8 MB  attn_out [B][S][1024]
  float*          btab = (float*)(ws + 48*MB);             // 256 KB bias table (log2e-scaled)
  float*          egf  = (float*)(ws + 48*MB + 256*1024);  // 16 KB exp(gate) f32
  unsigned short* egb  = (unsigned short*)(ws + 48*MB + 272*1024); // 8 KB exp(gate) bf16

  fused_prep_kernel<<<dim3(MTOT + 4096 + 256 + 16), dim3(256), 0, stream>>>(
      hs, lnw, rel, gate, qw, kw, vw, ow, xbf, btab, egf, egb, wqkv, wo);
  // fused projections: z=0 q, z=1 k, z=2 v'^T (block roles swapped for z=2)
  gemm128<0><<<dim3(MTOT/128, DMODEL/128, 3), dim3(256), 0, stream>>>(
      xbf, wqkv, qb, kb, vt, nullptr, nullptr, egf);
  attn_kernel<<<dim3(512), dim3(256), 0, stream>>>(
      qb, kb, vt, btab, egb, ao);
  gemm128<1><<<dim3(MTOT/128, DMODEL/128, 1), dim3(256), 0, stream>>>(
      ao, wo, nullptr, nullptr, nullptr, hs, out, nullptr);
}

// Round 20
// 133.085 us; speedup vs baseline: 1.0086x; 1.0086x over previous
//
#include <hip/hip_runtime.h>
#include <hip/hip_bf16.h>
#include <math.h>

typedef __attribute__((ext_vector_type(8))) short short8;
typedef __attribute__((ext_vector_type(4))) float f32x4;

#define S_LEN   2048
#define DMODEL  1024
#define NHEAD   16
#define HDK     64
#define NBATCH  2
#define MTOT    (NBATCH*S_LEN)   // 4096
#define LOG2E   1.4426950408889634f

__device__ __forceinline__ unsigned short f2bf(float f) {
  union { float f; unsigned u; } c; c.f = f;
  unsigned r = c.u + 0x7FFFu + ((c.u >> 16) & 1u);
  return (unsigned short)(r >> 16);
}

__device__ __forceinline__ short8 lds_ld16(const unsigned short* p) {
  return *reinterpret_cast<const short8*>(p);   // 16B-aligned load
}

__device__ __forceinline__ void gload_lds16(const unsigned short* g, unsigned short* l) {
  __builtin_amdgcn_global_load_lds(
      (const __attribute__((address_space(1))) unsigned int*)g,
      (__attribute__((address_space(3))) unsigned int*)l, 16, 0, 0);
}

// ---------- fused prep: rmsnorm (blocks 0..4095) + weight transpose (4096..8191)
//            + bias table (8192..8447) + exp(gate) (8448..8463) ----------
__global__ __launch_bounds__(256) void fused_prep_kernel(
    const float* __restrict__ hs, const float* __restrict__ lnw,
    const float* __restrict__ rel_emb, const float* __restrict__ gmask,
    const float* __restrict__ qw, const float* __restrict__ kw,
    const float* __restrict__ vw, const float* __restrict__ ow,
    unsigned short* __restrict__ xo, float* __restrict__ btab,
    float* __restrict__ egf, unsigned short* __restrict__ egb,
    unsigned short* __restrict__ wqkv, unsigned short* __restrict__ wo) {
  const int blk = blockIdx.x, t = threadIdx.x;
  if (blk < MTOT) {
    // ---- RMSNorm -> bf16 ----
    const int row = blk;
    const float4 v = ((const float4*)(hs + (size_t)row*DMODEL))[t];
    float ss = v.x*v.x + v.y*v.y + v.z*v.z + v.w*v.w;
    #pragma unroll
    for (int off = 32; off >= 1; off >>= 1) ss += __shfl_xor(ss, off, 64);
    __shared__ float wsum[4];
    if ((t & 63) == 0) wsum[t >> 6] = ss;
    __syncthreads();
    float tot = wsum[0] + wsum[1] + wsum[2] + wsum[3];
    float sc = rsqrtf(tot * (1.0f/DMODEL) + 1e-6f);
    const float4 lw = ((const float4*)lnw)[t];
    uint2 o;
    o.x = (unsigned)f2bf(v.x*sc*lw.x) | ((unsigned)f2bf(v.y*sc*lw.y) << 16);
    o.y = (unsigned)f2bf(v.z*sc*lw.z) | ((unsigned)f2bf(v.w*sc*lw.w) << 16);
    ((uint2*)(xo + (size_t)row*DMODEL))[t] = o;
  } else if (blk < MTOT + 4096) {
    // ---- weight transpose + bf16: w[k][n] -> wt[n][k] ----
    int bb = blk - MTOT;
    int z = bb >> 10, rem = bb & 1023;
    const float* src = (z==0)?qw:(z==1)?kw:(z==2)?vw:ow;
    unsigned short* dst = (z<3) ? (wqkv + (size_t)z*DMODEL*DMODEL) : wo;
    __shared__ float tile[32][33];
    int n0 = (rem & 31)*32, k0 = (rem >> 5)*32;
    int tx = t & 31, ty = t >> 5;
    for (int r = ty; r < 32; r += 8)
      tile[r][tx] = src[(size_t)(k0+r)*DMODEL + n0 + tx];
    __syncthreads();
    for (int r = ty; r < 32; r += 8)
      dst[(size_t)(n0+r)*DMODEL + k0 + tx] = f2bf(tile[tx][r]);
  } else if (blk < MTOT + 4096 + 256) {
    // ---- relative-position bias table: btab[h][rel+2047], pre-scaled by log2e ----
    int idx = (blk - MTOT - 4096)*256 + t;
    if (idx >= NHEAD*4095) return;
    int h = idx / 4095, rp = idx % 4095, rel = rp - 2047;
    int bucket = (rel > 0) ? 16 : 0;
    int n = (rel < 0) ? -rel : rel;
    int v;
    if (n < 8) v = n;
    else {
      float lrv = logf((float)n * 0.125f) / 2.7725887f * 8.0f;  // log(n/8)/log(16)*8
      v = 8 + (int)lrv;
      if (v > 15) v = 15;
    }
    btab[idx] = rel_emb[(size_t)(bucket + v)*NHEAD + h] * LOG2E;
  } else {
    // ---- gate exponentials: egf = exp(gate) f32, egb = bf16 ----
    int i = (blk - MTOT - 4096 - 256)*256 + t;   // 0..4095
    float e = __expf(gmask[i]);
    egf[i] = e;
    egb[i] = f2bf(e);
  }
}

// ---------- 128x128 tile MFMA GEMM, BK=64, swizzled staging (r14/r16 proven) ----------
// EPI=0 (fused projections), z: 0 -> q*log2e [BH][S][64]; 1 -> k [BH][S][64];
//                            2 -> V'^T = exp(gate)*v in [B][1024][S] (block roles swapped)
// EPI=1: write f32 Of = resid + acc
template<int EPI>
__global__ __launch_bounds__(256) void gemm128(
    const unsigned short* __restrict__ X,
    const unsigned short* __restrict__ W,
    unsigned short* __restrict__ Oq, unsigned short* __restrict__ Ok,
    unsigned short* __restrict__ Ov,
    const float* __restrict__ resid, float* __restrict__ Of,
    const float* __restrict__ escale) {
  __shared__ unsigned short As[128*64];   // [row][granule ^ (row&7)], linear dest
  __shared__ unsigned short Bs[128*64];
  const int z = blockIdx.z;
  int m0, n0;
  const unsigned short *Ap, *Bp;
  if (EPI == 0 && z == 2) {               // V'^T: A = Wv (1024 rows), B = x (4096 rows)
    m0 = blockIdx.y*128; n0 = blockIdx.x*128;
    Ap = W + (size_t)2*DMODEL*DMODEL; Bp = X;
  } else {
    m0 = blockIdx.x*128; n0 = blockIdx.y*128;
    Ap = X; Bp = W + ((EPI==0) ? (size_t)z*DMODEL*DMODEL : 0);
  }
  const int t = threadIdx.x, lane = t & 63, w = t >> 6;
  const int g = lane >> 4, lr = lane & 15;
  const int wr = (w >> 1)*64, wc = (w & 1)*64;

  f32x4 acc[4][4];
  #pragma unroll
  for (int mi = 0; mi < 4; mi++)
    #pragma unroll
    for (int ni = 0; ni < 4; ni++) acc[mi][ni] = (f32x4){0.f,0.f,0.f,0.f};

  const unsigned short* ag[4]; const unsigned short* bg[4];
  unsigned short* al[4]; unsigned short* bl[4];
  #pragma unroll
  for (int i = 0; i < 4; i++) {
    int slot = t + i*256, row = slot >> 3, c8 = slot & 7;
    int cs = c8 ^ (row & 7);
    ag[i] = Ap + (size_t)(m0 + row)*DMODEL + cs*8;
    bg[i] = Bp + (size_t)(n0 + row)*DMODEL + cs*8;
    al[i] = As + slot*8;
    bl[i] = Bs + slot*8;
  }

  for (int kk = 0; kk < DMODEL; kk += 64) {
    #pragma unroll
    for (int i = 0; i < 4; i++) {
      gload_lds16(ag[i] + kk, al[i]);
      gload_lds16(bg[i] + kk, bl[i]);
    }
    __syncthreads();            // drains vmcnt -> tile staged
    #pragma unroll
    for (int ks = 0; ks < 2; ks++) {
      short8 af[4], bfr[4];
      #pragma unroll
      for (int mi = 0; mi < 4; mi++) {
        int R = wr + mi*16 + lr;
        af[mi] = lds_ld16(As + R*64 + (((ks*4 + g) ^ (R & 7)) << 3));
      }
      #pragma unroll
      for (int ni = 0; ni < 4; ni++) {
        int R = wc + ni*16 + lr;
        bfr[ni] = lds_ld16(Bs + R*64 + (((ks*4 + g) ^ (R & 7)) << 3));
      }
      #pragma unroll
      for (int mi = 0; mi < 4; mi++)
        #pragma unroll
        for (int ni = 0; ni < 4; ni++)
          acc[mi][ni] = __builtin_amdgcn_mfma_f32_16x16x32_bf16(af[mi], bfr[ni], acc[mi][ni], 0, 0, 0);
    }
    __syncthreads();            // reads done before next stage
  }

  if (EPI == 0) {
    if (z < 2) {
      unsigned short* dst = (z == 0) ? Oq : Ok;
      const float osc = (z == 0) ? LOG2E : 1.0f;
      #pragma unroll
      for (int mi = 0; mi < 4; mi++) {
        #pragma unroll
        for (int r = 0; r < 4; r++) {
          int m = m0 + wr + mi*16 + g*4 + r;
          int b = m >> 11, s = m & (S_LEN-1);
          unsigned short* drow = dst + ((size_t)b*NHEAD*S_LEN + s)*HDK;
          #pragma unroll
          for (int ni = 0; ni < 4; ni++) {
            int n = n0 + wc + ni*16 + lr;
            int h = n >> 6, dcol = n & 63;
            drow[(size_t)h*S_LEN*HDK + dcol] = f2bf(acc[mi][ni][r] * osc);
          }
        }
      }
    } else {
      #pragma unroll
      for (int ni = 0; ni < 4; ni++) {
        int n = n0 + wc + ni*16 + lr;
        int b = n >> 11, s = n & (S_LEN-1);
        float e = escale[n];                 // exp(gate) folded into V'
        #pragma unroll
        for (int mi = 0; mi < 4; mi++)
          #pragma unroll
          for (int r = 0; r < 4; r++) {
            int m = m0 + wr + mi*16 + g*4 + r;
            Ov[((size_t)b*DMODEL + m)*S_LEN + s] = f2bf(acc[mi][ni][r] * e);
          }
      }
    }
  } else {
    #pragma unroll
    for (int mi = 0; mi < 4; mi++) {
      #pragma unroll
      for (int r = 0; r < 4; r++) {
        int m = m0 + wr + mi*16 + g*4 + r;
        const float* rrow = resid + (size_t)m*DMODEL;
        float* orow = Of + (size_t)m*DMODEL;
        #pragma unroll
        for (int ni = 0; ni < 4; ni++) {
          int n = n0 + wc + ni*16 + lr;
          orow[n] = rrow[n] + acc[mi][ni][r];
        }
      }
    }
  }
}

// ---------- flash attention: LDS-staged K/V', swapped QK^T, no-max softmax1 (r10/r16 proven) ----------
// Gate folded into V'; denominator via extra MFMA column of exp(gate); far-tile
// position bias injected via MFMA C-init. grid 512 (bijective XCD remap),
// block 256 = 4 waves x 2 sets of 16 q-rows. LDS staging kept: it amortizes K/V
// loads 4x across waves (r9's direct-global variant was L2-latency-bound, -70%).
__global__ __launch_bounds__(256, 2) void attn_kernel(
    const unsigned short* __restrict__ Qg,
    const unsigned short* __restrict__ Kg,
    const unsigned short* __restrict__ Vtg,
    const float* __restrict__ btab,
    const unsigned short* __restrict__ egb,
    unsigned short* __restrict__ Og) {
  __shared__ __align__(16) unsigned short Kl[2][64][64];   // [buf][key][d-granule ^ key&7]
  __shared__ __align__(16) unsigned short Vl[2][64][64];   // [buf][d][key-granule ^ d&7]
  __shared__ __align__(16) unsigned short Pl[4][16*64];    // per-wave P

  const int flat = blockIdx.x;
  const int xcd = flat & 7, j = flat >> 3;
  const int bh = xcd*4 + (j >> 4), qx = j & 15;
  const int b = bh >> 4, h = bh & 15;
  const int q0 = qx * 128;

  const int t = threadIdx.x, w = t >> 6, lane = t & 63;
  const int g = lane >> 4, lr = lane & 15, l7 = lane & 7;
  const int srow0 = t >> 3, sg0 = t & 7, srow1 = srow0 + 32;
  const int swz = (sg0 ^ (srow0 & 7)) << 3;                // srow1&7 == srow0&7

  const unsigned short* Qb = Qg  + (size_t)bh*S_LEN*HDK;
  const unsigned short* Kb = Kg  + (size_t)bh*S_LEN*HDK;
  const unsigned short* Vb = Vtg + (size_t)bh*HDK*S_LEN;   // [d][s], gate-folded
  const unsigned short* ge = egb + (size_t)b*S_LEN;        // exp(gate) bf16

  // ---- Q fragments: wave owns q rows [q0+w*32, +32), two sets of 16 ----
  const int qs0A = q0 + w*32, qs0B = qs0A + 16;
  short8 qfA0 = *reinterpret_cast<const short8*>(Qb + (size_t)(qs0A+lr)*HDK + g*8);
  short8 qfA1 = *reinterpret_cast<const short8*>(Qb + (size_t)(qs0A+lr)*HDK + 32 + g*8);
  short8 qfB0 = *reinterpret_cast<const short8*>(Qb + (size_t)(qs0B+lr)*HDK + g*8);
  short8 qfB1 = *reinterpret_cast<const short8*>(Qb + (size_t)(qs0B+lr)*HDK + 32 + g*8);

  f32x4 accA[4], accB[4], l4A, l4B;
  #pragma unroll
  for (int n = 0; n < 4; n++) { accA[n] = (f32x4){0.f,0.f,0.f,0.f}; accB[n] = (f32x4){0.f,0.f,0.f,0.f}; }
  l4A = (f32x4){0.f,0.f,0.f,0.f}; l4B = (f32x4){0.f,0.f,0.f,0.f};

  const float* btb = btab + (size_t)h*4095 + 2047;
  const float cpos = btb[91];    // bucket saturates for |rel| >= 91
  const float cneg = btb[-91];

  // ---- prologue: stage tile 0 ----
  {
    *reinterpret_cast<uint4*>(&Kl[0][srow0][swz]) =
        *reinterpret_cast<const uint4*>(Kb + (size_t)srow0*HDK + sg0*8);
    *reinterpret_cast<uint4*>(&Kl[0][srow1][swz]) =
        *reinterpret_cast<const uint4*>(Kb + (size_t)srow1*HDK + sg0*8);
    *reinterpret_cast<uint4*>(&Vl[0][srow0][swz]) =
        *reinterpret_cast<const uint4*>(Vb + (size_t)srow0*S_LEN + sg0*8);
    *reinterpret_cast<uint4*>(&Vl[0][srow1][swz]) =
        *reinterpret_cast<const uint4*>(Vb + (size_t)srow1*S_LEN + sg0*8);
  }

  char* prow = (char*)&Pl[w][0] + lr*128;   // this lane's P row (q = lr)

  int cur = 0;
  const int NT = S_LEN/64;
  for (int kt = 0; kt < NT; ++kt) {
    const int key0 = kt*64;
    __syncthreads();   // buf[cur] staged; all reads of buf[cur^1] done

    uint4 nk0, nk1, nv0, nv1;
    const bool pf = (kt + 1 < NT);
    if (pf) {
      nk0 = *reinterpret_cast<const uint4*>(Kb + (size_t)(key0+64+srow0)*HDK + sg0*8);
      nk1 = *reinterpret_cast<const uint4*>(Kb + (size_t)(key0+64+srow1)*HDK + sg0*8);
      nv0 = *reinterpret_cast<const uint4*>(Vb + (size_t)srow0*S_LEN + key0+64 + sg0*8);
      nv1 = *reinterpret_cast<const uint4*>(Vb + (size_t)srow1*S_LEN + key0+64 + sg0*8);
    }

    // ---- K fragments (A-frag: row=key=n*16+lr, k=d) ----
    short8 bk[4][2];
    #pragma unroll
    for (int n = 0; n < 4; n++) {
      const unsigned short* kr = &Kl[cur][n*16 + lr][0];
      bk[n][0] = lds_ld16(kr + ((g ^ l7) << 3));
      bk[n][1] = lds_ld16(kr + (((4 + g) ^ l7) << 3));
    }
    // ---- V' fragments (B-frag: k=key, col=d=n*16+lr), shared by both sets ----
    short8 bv[2][4];
    #pragma unroll
    for (int c = 0; c < 2; c++)
      #pragma unroll
      for (int n = 0; n < 4; n++)
        bv[c][n] = lds_ld16(&Vl[cur][n*16 + lr][((4*c + g) ^ l7) << 3]);
    // ---- G fragments: col0 = exp(gate_k), cols1-15 = 0 (from global, L1-hot) ----
    short8 gv[2];
    #pragma unroll
    for (int c = 0; c < 2; c++) {
      short8 z8 = (short8){0,0,0,0,0,0,0,0};
      if (lr == 0)
        z8 = *reinterpret_cast<const short8*>(ge + key0 + c*32 + g*8);
      gv[c] = z8;
    }

#define PROCESS_SET(qf0_, qf1_, qs0_, acc_, l4_)                                      \
    {                                                                                 \
      const int dband = key0 - (qs0_);                                                \
      const bool band = (dband > -154 && dband < 106);                                \
      const float cc = band ? 0.f : ((dband > 0) ? cpos : cneg);                      \
      f32x4 zc = (f32x4){cc, cc, cc, cc};   /* far-tile bias via C-init */            \
      f32x4 sv[4];                                                                    \
      __builtin_amdgcn_s_setprio(1);                                                  \
      _Pragma("unroll") for (int n = 0; n < 4; n++) {                                 \
        sv[n] = __builtin_amdgcn_mfma_f32_16x16x32_bf16(bk[n][0], qf0_, zc, 0, 0, 0); \
        sv[n] = __builtin_amdgcn_mfma_f32_16x16x32_bf16(bk[n][1], qf1_, sv[n], 0, 0, 0); \
      }                                                                               \
      __builtin_amdgcn_s_setprio(0);                                                  \
      if (band) {                                                                     \
        const float* btq = btb + (dband - lr);                                        \
        _Pragma("unroll") for (int n = 0; n < 4; n++)                                 \
          _Pragma("unroll") for (int r = 0; r < 4; r++)                               \
            sv[n][r] += btq[n*16 + g*4 + r];                                          \
      }                                                                               \
      _Pragma("unroll") for (int n = 0; n < 4; n++)                                   \
        _Pragma("unroll") for (int r = 0; r < 4; r++)                                 \
          sv[n][r] = exp2f(sv[n][r]);                                                 \
      _Pragma("unroll") for (int n = 0; n < 4; n++) {                                 \
        unsigned plo_, phi_;                                                          \
        asm("v_cvt_pk_bf16_f32 %0, %1, %2" : "=v"(plo_) : "v"(sv[n][0]), "v"(sv[n][1])); \
        asm("v_cvt_pk_bf16_f32 %0, %1, %2" : "=v"(phi_) : "v"(sv[n][2]), "v"(sv[n][3])); \
        uint2 pw_; pw_.x = plo_; pw_.y = phi_;                                        \
        *reinterpret_cast<uint2*>(prow + ((((2*n + (g>>1)) ^ l7) << 4) + ((g & 1) << 3))) = pw_; \
      }                                                                               \
      __builtin_amdgcn_s_setprio(1);                                                  \
      _Pragma("unroll") for (int c = 0; c < 2; c++) {                                 \
        short8 pa_ = lds_ld16((const unsigned short*)(prow + (((4*c + g) ^ l7) << 4))); \
        _Pragma("unroll") for (int n = 0; n < 4; n++)                                 \
          acc_[n] = __builtin_amdgcn_mfma_f32_16x16x32_bf16(pa_, bv[c][n], acc_[n], 0, 0, 0); \
        l4_ = __builtin_amdgcn_mfma_f32_16x16x32_bf16(pa_, gv[c], l4_, 0, 0, 0);      \
      }                                                                               \
      __builtin_amdgcn_s_setprio(0);                                                  \
    }

    PROCESS_SET(qfA0, qfA1, qs0A, accA, l4A)
    PROCESS_SET(qfB0, qfB1, qs0B, accB, l4B)
#undef PROCESS_SET

    // ---- write next tile into the other buffer ----
    if (pf) {
      *reinterpret_cast<uint4*>(&Kl[cur^1][srow0][swz]) = nk0;
      *reinterpret_cast<uint4*>(&Kl[cur^1][srow1][swz]) = nk1;
      *reinterpret_cast<uint4*>(&Vl[cur^1][srow0][swz]) = nv0;
      *reinterpret_cast<uint4*>(&Vl[cur^1][srow1][swz]) = nv1;
    }
    cur ^= 1;
  }

  // ---- finalize: l(q=g*4+r) lives on lane g*16 (col 0), reg r; denom = l + 1 ----
#define FINAL_SET(acc_, l4_, qs0_)                                                    \
  {                                                                                   \
    _Pragma("unroll") for (int r = 0; r < 4; r++) {                                   \
      float lq = __shfl(l4_[r], g*16);                                                \
      float inv = 1.0f / (lq + 1.0f);                                                 \
      int srw = (qs0_) + g*4 + r;                                                     \
      unsigned short* orow = Og + ((size_t)b*S_LEN + srw)*DMODEL + h*HDK;             \
      _Pragma("unroll") for (int n = 0; n < 4; n++)                                   \
        orow[n*16 + lr] = f2bf(acc_[n][r] * inv);                                     \
    }                                                                                 \
  }
  FINAL_SET(accA, l4A, qs0A)
  FINAL_SET(accB, l4B, qs0B)
#undef FINAL_SET
}

extern "C" void kernel_launch(void* const* d_in, const int* in_sizes, int n_in,
                              void* d_out, int out_size, void* d_ws, size_t ws_size,
                              hipStream_t stream) {
  const float* hs   = (const float*)d_in[0];
  const float* gate = (const float*)d_in[1];
  const float* lnw  = (const float*)d_in[2];
  const float* qw   = (const float*)d_in[3];
  const float* kw   = (const float*)d_in[4];
  const float* vw   = (const float*)d_in[5];
  const float* ow   = (const float*)d_in[6];
  const float* rel  = (const float*)d_in[7];
  float* out = (float*)d_out;

  char* ws = (char*)d_ws;
  const size_t MB = 1ull << 20;
  unsigned short* xbf  = (unsigned short*)(ws);            // 8 MB  x (bf16)
  unsigned short* wqkv = (unsigned short*)(ws + 8*MB);     // 6 MB  q/k/v weights^T
  unsigned short* wo   = (unsigned short*)(ws + 14*MB);    // 2 MB  o weight^T
  unsigned short* qb   = (unsigned short*)(ws + 16*MB);    // 8 MB  q [BH][S][64] (log2e-scaled)
  unsigned short* kb   = (unsigned short*)(ws + 24*MB);    // 8 MB  k [BH][S][64]
  unsigned short* vt   = (unsigned short*)(ws + 32*MB);    // 8 MB  v'^T [B][1024][S] (gate-folded)
  unsigned short* ao   = (unsigned short*)(ws + 40*MB);    // 8 MB  attn_out [B][S][1024]
  float*          btab = (float*)(ws + 48*MB);             // 256 KB bias table (log2e-scaled)
  float*          egf  = (float*)(ws + 48*MB + 256*1024);  // 16 KB exp(gate) f32
  unsigned short* egb  = (unsigned short*)(ws + 48*MB + 272*1024); // 8 KB exp(gate) bf16

  fused_prep_kernel<<<dim3(MTOT + 4096 + 256 + 16), dim3(256), 0, stream>>>(
      hs, lnw, rel, gate, qw, kw, vw, ow, xbf, btab, egf, egb, wqkv, wo);
  // fused projections: z=0 q, z=1 k, z=2 v'^T (block roles swapped for z=2)
  gemm128<0><<<dim3(MTOT/128, DMODEL/128, 3), dim3(256), 0, stream>>>(
      xbf, wqkv, qb, kb, vt, nullptr, nullptr, egf);
  attn_kernel<<<dim3(512), dim3(256), 0, stream>>>(
      qb, kb, vt, btab, egb, ao);
  gemm128<1><<<dim3(MTOT/128, DMODEL/128, 1), dim3(256), 0, stream>>>(
      ao, wo, nullptr, nullptr, nullptr, hs, out, nullptr);
}